// Round 2
// baseline (8076.250 us; speedup 1.0000x reference)
//
#include <hip/hip_runtime.h>
#include <hip/hip_bf16.h>
#include <math.h>

#ifndef M_PI
#define M_PI 3.14159265358979323846
#endif

typedef unsigned short u16;

#define NB   16
#define CIN  256
#define CH   128
#define HW   10000
#define NA   100
#define NR   100

__device__ __forceinline__ float bf2f(u16 v) {
  return __uint_as_float(((unsigned int)v) << 16);
}
__device__ __forceinline__ u16 f2bf(float f) {
  unsigned int u = __float_as_uint(f);
  u += 0x7fffu + ((u >> 16) & 1u);   // round-to-nearest-even
  return (u16)(u >> 16);
}

// ---------------------------------------------------------------------------
// prep: weight transposes + per-angle cos/sin table (float64, matches numpy)
// ---------------------------------------------------------------------------
__global__ void k_prep(const float* __restrict__ w1, const float* __restrict__ w2,
                       const float* __restrict__ w3, float* __restrict__ w1t,
                       float* __restrict__ w2t, float* __restrict__ w3t,
                       double* __restrict__ trig) {
  int t = blockIdx.x * blockDim.x + threadIdx.x;
  if (t < NA) {
#pragma clang fp contract(off)
    double theta = (double)t * (M_PI / 100.0);
    double irho  = 142.0 / 99.0;   // (floor(sqrt(2*100^2))+1)/(numRho-1)
    trig[2 * t]     = cos(theta) / irho;
    trig[2 * t + 1] = sin(theta) / irho;
  }
  if (t < CIN * CH) {
    int k = t / CH, c = t % CH;
    w1t[t] = w1[c * CIN + k];
  }
  if (t < 9 * CH * CH) {
    int tap = t / (CH * CH);
    int rem = t - tap * (CH * CH);
    int ci = rem / CH, co = rem & (CH - 1);
    w2t[t] = w2[(co * CH + ci) * 9 + tap];
    w3t[t] = w3[(co * CH + ci) * 9 + tap];
  }
}

// ---------------------------------------------------------------------------
// idx8[a][w][j]: rho index as u8, per-wave-padded layout. wave w owns pixels
// [w*625, (w+1)*625); row stride 632 keeps uchar4 loads 4B-aligned.
// r = clip(rint(xx*cos_t + yy*sin_t) + 50, 0, 99)   (exact f64, no fma)
// ---------------------------------------------------------------------------
__global__ void k_idx(const double* __restrict__ trig, unsigned char* __restrict__ idx8) {
#pragma clang fp contract(off)
  int a = blockIdx.y;
  int p = blockIdx.x * blockDim.x + threadIdx.x;
  if (p >= HW) return;
  double ct = trig[2 * a], st = trig[2 * a + 1];
  int i = p / 100;
  int j = p - i * 100;
  double s = (double)(j - 50) * ct + (double)(i - 50) * st;
  int r = (int)rint(s) + 50;
  r = r < 0 ? 0 : (r > 99 ? 99 : r);
  int w  = p / 625;
  int jj = p - w * 625;
  idx8[((size_t)a * 16 + w) * 632 + jj] = (unsigned char)r;
}

// ---------------------------------------------------------------------------
// conv1: 1x1 conv (CIN=256 -> CH=128) + BN + ReLU, x[N][CIN][HW] f32
//   -> h1t[N][HW][CH] bf16.  (unchanged)
// ---------------------------------------------------------------------------
__global__ void __launch_bounds__(256)
k_conv1(const float* __restrict__ x, const float* __restrict__ w1t,
        const float* __restrict__ pb, const float* __restrict__ pg,
        const float* __restrict__ pbe, u16* __restrict__ h1t) {
  __shared__ float xT[32][64];
  __shared__ float wT[32][128];
  int n  = blockIdx.y;
  int m0 = blockIdx.x * 64;
  int t  = threadIdx.x;
  int tx = t & 31;
  int ty = t >> 5;
  float acc[8][4] = {};

  for (int k0 = 0; k0 < CIN; k0 += 32) {
#pragma unroll
    for (int q = 0; q < 8; ++q) {
      int e = t + q * 256;
      int kk = e >> 6, mm = e & 63;
      int hw = m0 + mm;
      xT[kk][mm] = (hw < HW) ? x[((size_t)n * CIN + k0 + kk) * HW + hw] : 0.f;
    }
#pragma unroll
    for (int q = 0; q < 16; ++q) {
      int e = t + q * 256;
      int kk = e >> 7, cc = e & 127;
      wT[kk][cc] = w1t[(size_t)(k0 + kk) * CH + cc];
    }
    __syncthreads();
#pragma unroll
    for (int kk = 0; kk < 32; ++kk) {
      float4 wv = *(const float4*)&wT[kk][tx * 4];
      float xv[8];
      *(float4*)&xv[0] = *(const float4*)&xT[kk][ty * 8];
      *(float4*)&xv[4] = *(const float4*)&xT[kk][ty * 8 + 4];
#pragma unroll
      for (int i = 0; i < 8; ++i) {
        acc[i][0] += xv[i] * wv.x;
        acc[i][1] += xv[i] * wv.y;
        acc[i][2] += xv[i] * wv.z;
        acc[i][3] += xv[i] * wv.w;
      }
    }
    __syncthreads();
  }

  int c0 = tx * 4;
  float sc[4], sh[4];
#pragma unroll
  for (int jj = 0; jj < 4; ++jj) {
    float s = pg[c0 + jj] / sqrtf(1.f + 1e-5f);
    sc[jj] = s;
    sh[jj] = pb[c0 + jj] * s + pbe[c0 + jj];
  }
#pragma unroll
  for (int i = 0; i < 8; ++i) {
    int m = m0 + ty * 8 + i;
    if (m < HW) {
      ushort4 pk;
      float y0 = fmaxf(acc[i][0] * sc[0] + sh[0], 0.f);
      float y1 = fmaxf(acc[i][1] * sc[1] + sh[1], 0.f);
      float y2 = fmaxf(acc[i][2] * sc[2] + sh[2], 0.f);
      float y3 = fmaxf(acc[i][3] * sc[3] + sh[3], 0.f);
      pk.x = f2bf(y0); pk.y = f2bf(y1); pk.z = f2bf(y2); pk.w = f2bf(y3);
      *(ushort4*)&h1t[((size_t)n * HW + m) * CH + c0] = pk;
    }
  }
}

// ---------------------------------------------------------------------------
// dht v2: block = (n, angle-pair), 1024 threads = 16 waves.
// Wave w owns pixels [w*625, (w+1)*625); lane = channel-pair (u32 load covers
// channels 2c,2c+1). Each pixel is loaded once and scattered to BOTH angles'
// bins (run-length compressed, flushed via LDS f32 atomics — conflict-free:
// 64 lanes stride-8B = 2 lanes/bank).
// ---------------------------------------------------------------------------
__global__ void __launch_bounds__(1024)
k_dht(const u16* __restrict__ h1t, const unsigned char* __restrict__ idx8,
      u16* __restrict__ dht) {
  __shared__ float bins[2][NR][CH];   // 102.4 KB
  int n  = blockIdx.y;
  int a0 = blockIdx.x * 2;
  int t  = threadIdx.x;
  int c  = t & 63;    // channel-pair: channels 2c, 2c+1
  int w  = t >> 6;    // wave id 0..15 -> pixel chunk

  for (int q = t; q < 2 * NR * CH; q += 1024) ((float*)bins)[q] = 0.f;
  __syncthreads();

  const int P0 = w * 625;
  const unsigned char* i0 = idx8 + ((size_t)a0 * 16 + w) * 632;
  const unsigned char* i1 = idx8 + ((size_t)(a0 + 1) * 16 + w) * 632;
  const u16* img = h1t + ((size_t)n * HW + P0) * CH + 2 * c;

  int   rc0 = -1, rc1 = -1;
  float s0x = 0.f, s0y = 0.f, s1x = 0.f, s1y = 0.f;

  for (int p = 0; p + 4 <= 625; p += 4) {
    uchar4 q0 = *(const uchar4*)(i0 + p);
    uchar4 q1 = *(const uchar4*)(i1 + p);
    unsigned int vv[4];
#pragma unroll
    for (int u = 0; u < 4; ++u)
      vv[u] = *(const unsigned int*)(img + (size_t)(p + u) * CH);
    int r0[4], r1[4];
    r0[0] = __builtin_amdgcn_readfirstlane(q0.x);
    r0[1] = __builtin_amdgcn_readfirstlane(q0.y);
    r0[2] = __builtin_amdgcn_readfirstlane(q0.z);
    r0[3] = __builtin_amdgcn_readfirstlane(q0.w);
    r1[0] = __builtin_amdgcn_readfirstlane(q1.x);
    r1[1] = __builtin_amdgcn_readfirstlane(q1.y);
    r1[2] = __builtin_amdgcn_readfirstlane(q1.z);
    r1[3] = __builtin_amdgcn_readfirstlane(q1.w);
#pragma unroll
    for (int u = 0; u < 4; ++u) {
      float vx = bf2f((u16)(vv[u] & 0xffffu));
      float vy = bf2f((u16)(vv[u] >> 16));
      if (r0[u] != rc0) {
        if (rc0 >= 0) {
          atomicAdd(&bins[0][rc0][2 * c],     s0x);
          atomicAdd(&bins[0][rc0][2 * c + 1], s0y);
        }
        rc0 = r0[u]; s0x = vx; s0y = vy;
      } else { s0x += vx; s0y += vy; }
      if (r1[u] != rc1) {
        if (rc1 >= 0) {
          atomicAdd(&bins[1][rc1][2 * c],     s1x);
          atomicAdd(&bins[1][rc1][2 * c + 1], s1y);
        }
        rc1 = r1[u]; s1x = vx; s1y = vy;
      } else { s1x += vx; s1y += vy; }
    }
  }
  { // tail pixel p = 624
    int p = 624;
    unsigned int v = *(const unsigned int*)(img + (size_t)p * CH);
    float vx = bf2f((u16)(v & 0xffffu));
    float vy = bf2f((u16)(v >> 16));
    int t0 = __builtin_amdgcn_readfirstlane(i0[p]);
    int t1 = __builtin_amdgcn_readfirstlane(i1[p]);
    if (t0 != rc0) {
      if (rc0 >= 0) {
        atomicAdd(&bins[0][rc0][2 * c],     s0x);
        atomicAdd(&bins[0][rc0][2 * c + 1], s0y);
      }
      rc0 = t0; s0x = vx; s0y = vy;
    } else { s0x += vx; s0y += vy; }
    if (t1 != rc1) {
      if (rc1 >= 0) {
        atomicAdd(&bins[1][rc1][2 * c],     s1x);
        atomicAdd(&bins[1][rc1][2 * c + 1], s1y);
      }
      rc1 = t1; s1x = vx; s1y = vy;
    } else { s1x += vx; s1y += vy; }
  }
  if (rc0 >= 0) {
    atomicAdd(&bins[0][rc0][2 * c],     s0x);
    atomicAdd(&bins[0][rc0][2 * c + 1], s0y);
  }
  if (rc1 >= 0) {
    atomicAdd(&bins[1][rc1][2 * c],     s1x);
    atomicAdd(&bins[1][rc1][2 * c + 1], s1y);
  }
  __syncthreads();

  for (int q = t; q < 2 * NR * CH; q += 1024) {
    int gg  = q / (NR * CH);
    int rem = q - gg * (NR * CH);
    int r   = rem >> 7;
    int cc  = rem & 127;
    dht[(((size_t)n * NA + a0 + gg) * NR + r) * CH + cc] = f2bf(bins[gg][r][cc]);
  }
}

// ---------------------------------------------------------------------------
// 3x3 conv + BN + ReLU over [A,R] spatial, channels-innermost bf16 input.
// OUT_MODE 0: bf16 [N][A][R][CH];  OUT_MODE 1: f32 [N][CH][A][R] (final)
// (unchanged)
// ---------------------------------------------------------------------------
template <int OUT_MODE>
__global__ void __launch_bounds__(256)
k_conv3x3(const u16* __restrict__ X, const float* __restrict__ wt,
          const float* __restrict__ pb, const float* __restrict__ pg,
          const float* __restrict__ pbe, void* __restrict__ out) {
  __shared__ float patch[32][68];
  __shared__ float wT[32][128];
  int n  = blockIdx.y;
  int m0 = blockIdx.x * 64;
  int t  = threadIdx.x;
  int tx = t & 31;
  int ty = t >> 5;
  float acc[8][4] = {};

  int av[8], rv[8], vld[8];
#pragma unroll
  for (int q = 0; q < 8; ++q) {
    int mm = ty + 8 * q;
    int m  = m0 + mm;
    av[q]  = m / 100;
    rv[q]  = m - av[q] * 100;
    vld[q] = (m < HW);
  }
  const size_t nbase = (size_t)n * NA * NR * CH;

  for (int tap = 0; tap < 9; ++tap) {
    int da = tap / 3 - 1, dr = tap - (tap / 3) * 3 - 1;
    for (int k0 = 0; k0 < CH; k0 += 32) {
#pragma unroll
      for (int q = 0; q < 8; ++q) {
        int aa = av[q] + da, rr = rv[q] + dr;
        float val = 0.f;
        if (vld[q] && aa >= 0 && aa < NA && rr >= 0 && rr < NR)
          val = bf2f(X[nbase + ((size_t)aa * NR + rr) * CH + k0 + tx]);
        patch[tx][ty + 8 * q] = val;
      }
#pragma unroll
      for (int q = 0; q < 16; ++q) {
        int e = t + q * 256;
        int kk = e >> 7, cc = e & 127;
        wT[kk][cc] = wt[((size_t)tap * CH + k0 + kk) * CH + cc];
      }
      __syncthreads();
#pragma unroll
      for (int kk = 0; kk < 32; ++kk) {
        float4 wv = *(const float4*)&wT[kk][tx * 4];
        float xv[8];
        *(float4*)&xv[0] = *(const float4*)&patch[kk][ty * 8];
        *(float4*)&xv[4] = *(const float4*)&patch[kk][ty * 8 + 4];
#pragma unroll
        for (int i = 0; i < 8; ++i) {
          acc[i][0] += xv[i] * wv.x;
          acc[i][1] += xv[i] * wv.y;
          acc[i][2] += xv[i] * wv.z;
          acc[i][3] += xv[i] * wv.w;
        }
      }
      __syncthreads();
    }
  }

  int c0 = tx * 4;
  float sc[4], sh[4];
#pragma unroll
  for (int jj = 0; jj < 4; ++jj) {
    float s = pg[c0 + jj] / sqrtf(1.f + 1e-5f);
    sc[jj] = s;
    sh[jj] = pb[c0 + jj] * s + pbe[c0 + jj];
  }
#pragma unroll
  for (int i = 0; i < 8; ++i) {
    int m = m0 + ty * 8 + i;
    if (m >= HW) continue;
    float y[4];
#pragma unroll
    for (int jj = 0; jj < 4; ++jj) y[jj] = fmaxf(acc[i][jj] * sc[jj] + sh[jj], 0.f);
    if (OUT_MODE == 0) {
      u16* o = (u16*)out;
      ushort4 pk;
      pk.x = f2bf(y[0]); pk.y = f2bf(y[1]); pk.z = f2bf(y[2]); pk.w = f2bf(y[3]);
      *(ushort4*)&o[((size_t)n * HW + m) * CH + c0] = pk;
    } else {
      float* o = (float*)out;
#pragma unroll
      for (int jj = 0; jj < 4; ++jj)
        o[((size_t)n * CH + c0 + jj) * HW + m] = y[jj];
    }
  }
}

// ---------------------------------------------------------------------------
extern "C" void kernel_launch(void* const* d_in, const int* in_sizes, int n_in,
                              void* d_out, int out_size, void* d_ws, size_t ws_size,
                              hipStream_t stream) {
  if (n_in < 13) return;
  const float* x   = (const float*)d_in[0];
  const float* w1  = (const float*)d_in[1];
  const float* b1  = (const float*)d_in[2];
  const float* g1  = (const float*)d_in[3];
  const float* be1 = (const float*)d_in[4];
  const float* w2  = (const float*)d_in[5];
  const float* b2  = (const float*)d_in[6];
  const float* g2  = (const float*)d_in[7];
  const float* be2 = (const float*)d_in[8];
  const float* w3  = (const float*)d_in[9];
  const float* b3  = (const float*)d_in[10];
  const float* g3  = (const float*)d_in[11];
  const float* be3 = (const float*)d_in[12];

  // workspace layout (all 256B-aligned)
  const size_t o_trig = 0;                         // 1600 (pad 2048)
  const size_t o_idx  = 2048;                      // idx8: 100*16*632 = 1,011,200 (slot 4 MB)
  const size_t o_w1t  = o_idx + 4000000;           // 131,072
  const size_t o_w2t  = o_w1t + 131072;            // 589,824
  const size_t o_w3t  = o_w2t + 589824;            // 589,824
  const size_t o_dht  = o_w3t + 589824;            // 40,960,000
  const size_t o_c2   = o_dht + 40960000;          // 40,960,000
  const size_t need   = o_c2 + 40960000;           // ~87.2 MB
  if (ws_size < need) return;

  char*          ws   = (char*)d_ws;
  double*        trig = (double*)(ws + o_trig);
  unsigned char* idx8 = (unsigned char*)(ws + o_idx);
  float*         w1t  = (float*)(ws + o_w1t);
  float*         w2t  = (float*)(ws + o_w2t);
  float*         w3t  = (float*)(ws + o_w3t);
  u16*           dht  = (u16*)(ws + o_dht);
  u16*           c2   = (u16*)(ws + o_c2);
  u16*           h1t  = (u16*)d_out;   // bf16 scratch inside f32 out (dead before conv3)

  k_prep<<<dim3(576), dim3(256), 0, stream>>>(w1, w2, w3, w1t, w2t, w3t, trig);
  k_idx<<<dim3(40, 100), dim3(256), 0, stream>>>(trig, idx8);
  k_conv1<<<dim3(157, 16), dim3(256), 0, stream>>>(x, w1t, b1, g1, be1, h1t);
  k_dht<<<dim3(50, 16), dim3(1024), 0, stream>>>(h1t, idx8, dht);
  k_conv3x3<0><<<dim3(157, 16), dim3(256), 0, stream>>>(dht, w2t, b2, g2, be2, (void*)c2);
  k_conv3x3<1><<<dim3(157, 16), dim3(256), 0, stream>>>(c2, w3t, b3, g3, be3, d_out);
}

// Round 4
// 2505.823 us; speedup vs baseline: 3.2230x; 3.2230x over previous
//
#include <hip/hip_runtime.h>
#include <hip/hip_bf16.h>
#include <math.h>

#ifndef M_PI
#define M_PI 3.14159265358979323846
#endif

typedef unsigned short u16;

#define CIN  256
#define CH   128
#define HW   10000
#define NA   100
#define NR   100

__device__ __forceinline__ float bf2f(u16 v) {
  return __uint_as_float(((unsigned int)v) << 16);
}
__device__ __forceinline__ u16 f2bf(float f) {
  unsigned int u = __float_as_uint(f);
  u += 0x7fffu + ((u >> 16) & 1u);   // round-to-nearest-even
  return (u16)(u >> 16);
}

// ---------------------------------------------------------------------------
// prep: weight transposes
//   w1t[k][c]        = w1[c][k]
//   w2t/w3t[tap][ci][co] = w[co][ci][tap]
// ---------------------------------------------------------------------------
__global__ void k_prep(const float* __restrict__ w1, const float* __restrict__ w2,
                       const float* __restrict__ w3, float* __restrict__ w1t,
                       float* __restrict__ w2t, float* __restrict__ w3t) {
  int t = blockIdx.x * blockDim.x + threadIdx.x;
  if (t < CIN * CH) {
    int k = t / CH, c = t % CH;
    w1t[t] = w1[c * CIN + k];
  }
  if (t < 9 * CH * CH) {
    int tap = t / (CH * CH);
    int rem = t - tap * (CH * CH);
    int ci = rem / CH, co = rem & (CH - 1);
    w2t[t] = w2[(co * CH + ci) * 9 + tap];
    w3t[t] = w3[(co * CH + ci) * 9 + tap];
  }
}

// ---------------------------------------------------------------------------
// csr: per angle, bucket pixels by rho bin (stable: ascending p within bin).
// Block = angle. Produces list[a][k] (u16 pixel ids, bin-sorted) and
// coff[a][r] (exclusive offsets, coff[a][100]=10000).
// r = clip(rint(xx*cos_t + yy*sin_t) + 50, 0, 99)   (exact f64, no fma)
// ---------------------------------------------------------------------------
__global__ void __launch_bounds__(256)
k_csr(u16* __restrict__ list, int* __restrict__ coff) {
#pragma clang fp contract(off)
  __shared__ unsigned char sidx[HW];
  __shared__ int cnt[NR];
  __shared__ int off[NR + 1];
  int a = blockIdx.x;
  int t = threadIdx.x;

  double theta = (double)a * (M_PI / 100.0);
  double irho  = 142.0 / 99.0;   // (floor(sqrt(2*100^2))+1)/(numRho-1)
  double ct = cos(theta) / irho;
  double st = sin(theta) / irho;

  if (t < NR) cnt[t] = 0;
  __syncthreads();

  for (int p = t; p < HW; p += 256) {
    int i = p / 100;
    int j = p - i * 100;
    double s = (double)(j - 50) * ct + (double)(i - 50) * st;
    int r = (int)rint(s) + 50;
    r = r < 0 ? 0 : (r > 99 ? 99 : r);
    sidx[p] = (unsigned char)r;
    atomicAdd(&cnt[r], 1);
  }
  __syncthreads();

  if (t == 0) {
    int acc = 0;
    for (int r = 0; r < NR; ++r) { off[r] = acc; acc += cnt[r]; }
    off[NR] = acc;   // == HW
  }
  __syncthreads();
  if (t <= NR) coff[a * (NR + 1) + t] = off[t];

  if (t < NR) {
    int k = off[t];
    unsigned char me = (unsigned char)t;
    u16* dst = list + (size_t)a * HW;
#pragma unroll 4
    for (int p = 0; p < HW; ++p) {
      if (sidx[p] == me) { dst[k] = (u16)p; ++k; }
    }
  }
}

// ---------------------------------------------------------------------------
// conv1: 1x1 conv (CIN=256 -> CH=128) + BN + ReLU, x[N][CIN][HW] f32
//   -> h1t[N][HW][CH] bf16.  (unchanged)
// ---------------------------------------------------------------------------
__global__ void __launch_bounds__(256)
k_conv1(const float* __restrict__ x, const float* __restrict__ w1t,
        const float* __restrict__ pb, const float* __restrict__ pg,
        const float* __restrict__ pbe, u16* __restrict__ h1t) {
  __shared__ float xT[32][64];
  __shared__ float wT[32][128];
  int n  = blockIdx.y;
  int m0 = blockIdx.x * 64;
  int t  = threadIdx.x;
  int tx = t & 31;
  int ty = t >> 5;
  float acc[8][4] = {};

  for (int k0 = 0; k0 < CIN; k0 += 32) {
#pragma unroll
    for (int q = 0; q < 8; ++q) {
      int e = t + q * 256;
      int kk = e >> 6, mm = e & 63;
      int hw = m0 + mm;
      xT[kk][mm] = (hw < HW) ? x[((size_t)n * CIN + k0 + kk) * HW + hw] : 0.f;
    }
#pragma unroll
    for (int q = 0; q < 16; ++q) {
      int e = t + q * 256;
      int kk = e >> 7, cc = e & 127;
      wT[kk][cc] = w1t[(size_t)(k0 + kk) * CH + cc];
    }
    __syncthreads();
#pragma unroll
    for (int kk = 0; kk < 32; ++kk) {
      float4 wv = *(const float4*)&wT[kk][tx * 4];
      float xv[8];
      *(float4*)&xv[0] = *(const float4*)&xT[kk][ty * 8];
      *(float4*)&xv[4] = *(const float4*)&xT[kk][ty * 8 + 4];
#pragma unroll
      for (int i = 0; i < 8; ++i) {
        acc[i][0] += xv[i] * wv.x;
        acc[i][1] += xv[i] * wv.y;
        acc[i][2] += xv[i] * wv.z;
        acc[i][3] += xv[i] * wv.w;
      }
    }
    __syncthreads();
  }

  int c0 = tx * 4;
  float sc[4], sh[4];
#pragma unroll
  for (int jj = 0; jj < 4; ++jj) {
    float s = pg[c0 + jj] / sqrtf(1.f + 1e-5f);
    sc[jj] = s;
    sh[jj] = pb[c0 + jj] * s + pbe[c0 + jj];
  }
#pragma unroll
  for (int i = 0; i < 8; ++i) {
    int m = m0 + ty * 8 + i;
    if (m < HW) {
      ushort4 pk;
      float y0 = fmaxf(acc[i][0] * sc[0] + sh[0], 0.f);
      float y1 = fmaxf(acc[i][1] * sc[1] + sh[1], 0.f);
      float y2 = fmaxf(acc[i][2] * sc[2] + sh[2], 0.f);
      float y3 = fmaxf(acc[i][3] * sc[3] + sh[3], 0.f);
      pk.x = f2bf(y0); pk.y = f2bf(y1); pk.z = f2bf(y2); pk.w = f2bf(y3);
      *(ushort4*)&h1t[((size_t)n * HW + m) * CH + c0] = pk;
    }
  }
}

// ---------------------------------------------------------------------------
// dht v3 (gather): block = (n, a) via XCD swizzle; 1024 thr = 16 waves.
// Lane = channel-pair (u32 covers 2 bf16 ch; wave covers all 128 ch).
// Wave w owns the rho bins whose CSR midpoint falls in its 1/16 pixel slice;
// accumulate bin in 2 registers, write straight to global. No LDS bins,
// no atomics, no data-dependent branches.
// ---------------------------------------------------------------------------
__global__ void __launch_bounds__(1024)
k_dht(const u16* __restrict__ h1t, const u16* __restrict__ list,
      const int* __restrict__ coff, u16* __restrict__ dht) {
  __shared__ int soff[NR + 1];
  int id = blockIdx.x;           // 0..1599
  int x  = id & 7;               // XCD
  int l  = id >> 3;              // 0..199
  int n  = (x << 1) | (l >= 100 ? 1 : 0);   // 2 images per XCD (~5MB in L2)
  int a  = (l >= 100) ? l - 100 : l;
  int t  = threadIdx.x;
  int c  = t & 63;               // channel pair
  int w  = t >> 6;               // wave 0..15

  if (t <= NR) soff[t] = coff[a * (NR + 1) + t];
  __syncthreads();

  const unsigned int* img = (const unsigned int*)(h1t + (size_t)n * HW * CH) + c;
  const u16* lst = list + (size_t)a * HW;
  unsigned int* out32 = (unsigned int*)(dht + ((size_t)(n * NA + a) * NR) * CH) + c;

  for (int r = 0; r < NR; ++r) {
    int o0 = soff[r], o1 = soff[r + 1];
    int owner = (o0 + ((o1 - o0) >> 1)) * 16 / HW;
    owner = owner > 15 ? 15 : owner;
    if (owner != w) continue;
    float ax = 0.f, ay = 0.f;
#pragma unroll 4
    for (int k = o0; k < o1; ++k) {
      int p = (int)lst[k];
      unsigned int v = img[(size_t)p << 6];
      ax += bf2f((u16)(v & 0xffffu));
      ay += bf2f((u16)(v >> 16));
    }
    unsigned int pk = (unsigned int)f2bf(ax) | ((unsigned int)f2bf(ay) << 16);
    out32[(size_t)r << 6] = pk;
  }
}

// ---------------------------------------------------------------------------
// 3x3 conv + BN + ReLU over [A,R] spatial, channels-innermost bf16 input.
// OUT_MODE 0: bf16 [N][A][R][CH];  OUT_MODE 1: f32 [N][CH][A][R] (final)
// (unchanged)
// ---------------------------------------------------------------------------
template <int OUT_MODE>
__global__ void __launch_bounds__(256)
k_conv3x3(const u16* __restrict__ X, const float* __restrict__ wt,
          const float* __restrict__ pb, const float* __restrict__ pg,
          const float* __restrict__ pbe, void* __restrict__ out) {
  __shared__ float patch[32][68];
  __shared__ float wT[32][128];
  int n  = blockIdx.y;
  int m0 = blockIdx.x * 64;
  int t  = threadIdx.x;
  int tx = t & 31;
  int ty = t >> 5;
  float acc[8][4] = {};

  int av[8], rv[8], vld[8];
#pragma unroll
  for (int q = 0; q < 8; ++q) {
    int mm = ty + 8 * q;
    int m  = m0 + mm;
    av[q]  = m / 100;
    rv[q]  = m - av[q] * 100;
    vld[q] = (m < HW);
  }
  const size_t nbase = (size_t)n * NA * NR * CH;

  for (int tap = 0; tap < 9; ++tap) {
    int da = tap / 3 - 1, dr = tap - (tap / 3) * 3 - 1;
    for (int k0 = 0; k0 < CH; k0 += 32) {
#pragma unroll
      for (int q = 0; q < 8; ++q) {
        int aa = av[q] + da, rr = rv[q] + dr;
        float val = 0.f;
        if (vld[q] && aa >= 0 && aa < NA && rr >= 0 && rr < NR)
          val = bf2f(X[nbase + ((size_t)aa * NR + rr) * CH + k0 + tx]);
        patch[tx][ty + 8 * q] = val;
      }
#pragma unroll
      for (int q = 0; q < 16; ++q) {
        int e = t + q * 256;
        int kk = e >> 7, cc = e & 127;
        wT[kk][cc] = wt[((size_t)tap * CH + k0 + kk) * CH + cc];
      }
      __syncthreads();
#pragma unroll
      for (int kk = 0; kk < 32; ++kk) {
        float4 wv = *(const float4*)&wT[kk][tx * 4];
        float xv[8];
        *(float4*)&xv[0] = *(const float4*)&patch[kk][ty * 8];
        *(float4*)&xv[4] = *(const float4*)&patch[kk][ty * 8 + 4];
#pragma unroll
        for (int i = 0; i < 8; ++i) {
          acc[i][0] += xv[i] * wv.x;
          acc[i][1] += xv[i] * wv.y;
          acc[i][2] += xv[i] * wv.z;
          acc[i][3] += xv[i] * wv.w;
        }
      }
      __syncthreads();
    }
  }

  int c0 = tx * 4;
  float sc[4], sh[4];
#pragma unroll
  for (int jj = 0; jj < 4; ++jj) {
    float s = pg[c0 + jj] / sqrtf(1.f + 1e-5f);
    sc[jj] = s;
    sh[jj] = pb[c0 + jj] * s + pbe[c0 + jj];
  }
#pragma unroll
  for (int i = 0; i < 8; ++i) {
    int m = m0 + ty * 8 + i;
    if (m >= HW) continue;
    float y[4];
#pragma unroll
    for (int jj = 0; jj < 4; ++jj) y[jj] = fmaxf(acc[i][jj] * sc[jj] + sh[jj], 0.f);
    if (OUT_MODE == 0) {
      u16* o = (u16*)out;
      ushort4 pk;
      pk.x = f2bf(y[0]); pk.y = f2bf(y[1]); pk.z = f2bf(y[2]); pk.w = f2bf(y[3]);
      *(ushort4*)&o[((size_t)n * HW + m) * CH + c0] = pk;
    } else {
      float* o = (float*)out;
#pragma unroll
      for (int jj = 0; jj < 4; ++jj)
        o[((size_t)n * CH + c0 + jj) * HW + m] = y[jj];
    }
  }
}

// ---------------------------------------------------------------------------
extern "C" void kernel_launch(void* const* d_in, const int* in_sizes, int n_in,
                              void* d_out, int out_size, void* d_ws, size_t ws_size,
                              hipStream_t stream) {
  if (n_in < 13) return;
  const float* x   = (const float*)d_in[0];
  const float* w1  = (const float*)d_in[1];
  const float* b1  = (const float*)d_in[2];
  const float* g1  = (const float*)d_in[3];
  const float* be1 = (const float*)d_in[4];
  const float* w2  = (const float*)d_in[5];
  const float* b2  = (const float*)d_in[6];
  const float* g2  = (const float*)d_in[7];
  const float* be2 = (const float*)d_in[8];
  const float* w3  = (const float*)d_in[9];
  const float* b3  = (const float*)d_in[10];
  const float* g3  = (const float*)d_in[11];
  const float* be3 = (const float*)d_in[12];

  // workspace layout (256B-aligned)
  const size_t o_list = 0;                          // u16[100][10000] = 2,000,000
  const size_t o_coff = 2000128;                    // int[100][101]   = 40,400
  const size_t o_w1t  = 2040576;                    // 131,072
  const size_t o_w2t  = o_w1t + 131072;             // 589,824
  const size_t o_w3t  = o_w2t + 589824;             // 589,824
  const size_t o_dht  = o_w3t + 589824;             // 40,960,000
  const size_t o_c2   = o_dht + 40960000;           // 40,960,000
  const size_t need   = o_c2 + 40960000;            // ~85.3 MB
  if (ws_size < need) return;

  char*  ws   = (char*)d_ws;
  u16*   list = (u16*)(ws + o_list);
  int*   coff = (int*)(ws + o_coff);
  float* w1t  = (float*)(ws + o_w1t);
  float* w2t  = (float*)(ws + o_w2t);
  float* w3t  = (float*)(ws + o_w3t);
  u16*   dht  = (u16*)(ws + o_dht);
  u16*   c2   = (u16*)(ws + o_c2);
  u16*   h1t  = (u16*)d_out;   // bf16 scratch inside f32 out (dead before conv3)

  k_prep<<<dim3(576), dim3(256), 0, stream>>>(w1, w2, w3, w1t, w2t, w3t);
  k_csr<<<dim3(100), dim3(256), 0, stream>>>(list, coff);
  k_conv1<<<dim3(157, 16), dim3(256), 0, stream>>>(x, w1t, b1, g1, be1, h1t);
  k_dht<<<dim3(1600), dim3(1024), 0, stream>>>(h1t, list, coff, dht);
  k_conv3x3<0><<<dim3(157, 16), dim3(256), 0, stream>>>(dht, w2t, b2, g2, be2, (void*)c2);
  k_conv3x3<1><<<dim3(157, 16), dim3(256), 0, stream>>>(c2, w3t, b3, g3, be3, d_out);
}

// Round 5
// 1289.585 us; speedup vs baseline: 6.2627x; 1.9431x over previous
//
#include <hip/hip_runtime.h>
#include <hip/hip_bf16.h>
#include <math.h>

#ifndef M_PI
#define M_PI 3.14159265358979323846
#endif

typedef unsigned short u16;
typedef short short8 __attribute__((ext_vector_type(8)));
typedef float f32x4 __attribute__((ext_vector_type(4)));

#define CIN  256
#define CH   128
#define HW   10000
#define NA   100
#define NR   100

__device__ __forceinline__ float bf2f(u16 v) {
  return __uint_as_float(((unsigned int)v) << 16);
}
__device__ __forceinline__ u16 f2bf(float f) {
  unsigned int u = __float_as_uint(f);
  u += 0x7fffu + ((u >> 16) & 1u);   // round-to-nearest-even
  return (u16)(u >> 16);
}

// ---------------------------------------------------------------------------
// prep: fragment-ready bf16 weights.
//  wbf1[kc8][nf8][l64][j8]        = w1[co][ci],  co=nf*16+(l&15), ci=kc*32+(l>>4)*8+j
//  wbf2/3[tap9][kc4][nf8][l64][j8]= w[co][ci][tap]
// ---------------------------------------------------------------------------
__global__ void k_prep(const float* __restrict__ w1, const float* __restrict__ w2,
                       const float* __restrict__ w3, u16* __restrict__ wbf1,
                       u16* __restrict__ wbf2, u16* __restrict__ wbf3) {
  int t = blockIdx.x * blockDim.x + threadIdx.x;
  if (t < 32768) {
    int j = t & 7, lp = (t >> 3) & 63, nf = (t >> 9) & 7, kc = t >> 12;
    int co = nf * 16 + (lp & 15);
    int ci = kc * 32 + (lp >> 4) * 8 + j;
    wbf1[t] = f2bf(w1[co * CIN + ci]);
  }
  if (t < 147456) {
    int j = t & 7, lp = (t >> 3) & 63, nf = (t >> 9) & 7, kc = (t >> 12) & 3, tap = t >> 14;
    int co = nf * 16 + (lp & 15);
    int ci = kc * 32 + (lp >> 4) * 8 + j;
    wbf2[t] = f2bf(w2[(co * CH + ci) * 9 + tap]);
    wbf3[t] = f2bf(w3[(co * CH + ci) * 9 + tap]);
  }
}

// ---------------------------------------------------------------------------
// csr: per angle, bucket pixels by rho bin (stable). (unchanged from R4)
// ---------------------------------------------------------------------------
__global__ void __launch_bounds__(256)
k_csr(u16* __restrict__ list, int* __restrict__ coff) {
#pragma clang fp contract(off)
  __shared__ unsigned char sidx[HW];
  __shared__ int cnt[NR];
  __shared__ int off[NR + 1];
  int a = blockIdx.x;
  int t = threadIdx.x;

  double theta = (double)a * (M_PI / 100.0);
  double irho  = 142.0 / 99.0;
  double ct = cos(theta) / irho;
  double st = sin(theta) / irho;

  if (t < NR) cnt[t] = 0;
  __syncthreads();

  for (int p = t; p < HW; p += 256) {
    int i = p / 100;
    int j = p - i * 100;
    double s = (double)(j - 50) * ct + (double)(i - 50) * st;
    int r = (int)rint(s) + 50;
    r = r < 0 ? 0 : (r > 99 ? 99 : r);
    sidx[p] = (unsigned char)r;
    atomicAdd(&cnt[r], 1);
  }
  __syncthreads();

  if (t == 0) {
    int acc = 0;
    for (int r = 0; r < NR; ++r) { off[r] = acc; acc += cnt[r]; }
    off[NR] = acc;
  }
  __syncthreads();
  if (t <= NR) coff[a * (NR + 1) + t] = off[t];

  if (t < NR) {
    int k = off[t];
    unsigned char me = (unsigned char)t;
    u16* dst = list + (size_t)a * HW;
#pragma unroll 4
    for (int p = 0; p < HW; ++p) {
      if (sidx[p] == me) { dst[k] = (u16)p; ++k; }
    }
  }
}

// ---------------------------------------------------------------------------
// xt: transpose+cast x[N][CIN][HW] f32 -> xt[N][HW][CIN] bf16
// ---------------------------------------------------------------------------
__global__ void __launch_bounds__(256)
k_xt(const float* __restrict__ x, u16* __restrict__ xt) {
  __shared__ u16 tl[64][70];
  int n = blockIdx.z, c0 = blockIdx.y * 64, h0 = blockIdx.x * 64;
  int t = threadIdx.x;
#pragma unroll
  for (int p = 0; p < 16; ++p) {            // read 4 cin-rows x 64 hw per pass
    int row = p * 4 + (t >> 6);
    int col = t & 63;
    int hw  = h0 + col;
    float v = (hw < HW) ? x[((size_t)n * CIN + c0 + row) * HW + hw] : 0.f;
    tl[row][col] = f2bf(v);
  }
  __syncthreads();
  int hr = t >> 2;                           // 64 hw rows
  int sc = (t & 3) * 16;                     // 16 cin per thread
  int hw = h0 + hr;
  if (hw < HW) {
    u16 vals[16];
#pragma unroll
    for (int j = 0; j < 16; ++j) vals[j] = tl[sc + j][hr];
    u16* dst = xt + ((size_t)n * HW + hw) * CIN + c0 + sc;
    *(uint4*)(dst)     = *(uint4*)&vals[0];
    *(uint4*)(dst + 8) = *(uint4*)&vals[8];
  }
}

// ---------------------------------------------------------------------------
// conv1 (MFMA GEMM): xt[N][HW][CIN] bf16 x wbf1 -> h1t[N][HW][CH] bf16
// block 256 thr = 4 waves (2x2); tile M=128 hw, N=128 co, K=256.
// ---------------------------------------------------------------------------
__global__ void __launch_bounds__(256)
k_conv1(const u16* __restrict__ xt, const u16* __restrict__ wbf1,
        const float* __restrict__ pb, const float* __restrict__ pg,
        const float* __restrict__ pbe, u16* __restrict__ h1t) {
  __shared__ uint4 lds4[4096];               // 64 KB: A tile 128 x 512B (swizzled)
  char* lds = (char*)lds4;
  int n  = blockIdx.y;
  int m0 = blockIdx.x * 128;
  int t  = threadIdx.x;
  int l  = t & 63, w = t >> 6, wm = w >> 1, wn = w & 1;

  {                                          // stage A: rows m, 512B each
    int r8  = t >> 5;                        // 8 rows per pass
    int seg = t & 31;                        // 16B segment
#pragma unroll
    for (int p = 0; p < 16; ++p) {
      int m  = p * 8 + r8;
      int hw = m0 + m;
      uint4 v = make_uint4(0, 0, 0, 0);
      if (hw < HW) v = *(const uint4*)(xt + ((size_t)n * HW + hw) * CIN + seg * 8);
      *(uint4*)(lds + m * 512 + ((seg * 16) ^ ((m & 31) << 4))) = v;
    }
  }
  __syncthreads();

  int kseg = (l >> 4) * 16;
  f32x4 acc[4][4];
  f32x4 zf = {0.f, 0.f, 0.f, 0.f};
#pragma unroll
  for (int i = 0; i < 4; ++i)
#pragma unroll
    for (int j = 0; j < 4; ++j) acc[i][j] = zf;

  for (int kc = 0; kc < 8; ++kc) {
    short8 afr[4], bfr[4];
#pragma unroll
    for (int fm = 0; fm < 4; ++fm) {
      int m = wm * 64 + fm * 16 + (l & 15);
      afr[fm] = *(const short8*)(lds + m * 512 + ((kc * 64 + kseg) ^ ((m & 31) << 4)));
    }
#pragma unroll
    for (int fn = 0; fn < 4; ++fn)
      bfr[fn] = *(const short8*)(wbf1 + (((size_t)kc * 8 + wn * 4 + fn) * 64 + l) * 8);
#pragma unroll
    for (int fm = 0; fm < 4; ++fm)
#pragma unroll
      for (int fn = 0; fn < 4; ++fn)
        acc[fm][fn] = __builtin_amdgcn_mfma_f32_16x16x32_bf16(afr[fm], bfr[fn], acc[fm][fn], 0, 0, 0);
  }

  float sc[4], sh[4];
#pragma unroll
  for (int fn = 0; fn < 4; ++fn) {
    int co = wn * 64 + fn * 16 + (l & 15);
    float s = pg[co] / sqrtf(1.f + 1e-5f);
    sc[fn] = s;
    sh[fn] = pb[co] * s + pbe[co];
  }

  __syncthreads();                           // done reading A tile
#pragma unroll
  for (int fm = 0; fm < 4; ++fm)
#pragma unroll
    for (int fn = 0; fn < 4; ++fn) {
      int co = wn * 64 + fn * 16 + (l & 15);
#pragma unroll
      for (int q = 0; q < 4; ++q) {
        int m = wm * 64 + fm * 16 + (l >> 4) * 4 + q;
        float y = fmaxf(acc[fm][fn][q] * sc[fn] + sh[fn], 0.f);
        *(u16*)(lds + m * 256 + ((co * 2) ^ ((m & 15) << 4))) = f2bf(y);
      }
    }
  __syncthreads();
#pragma unroll
  for (int p = 0; p < 8; ++p) {
    int e = p * 256 + t;
    int m = e >> 4;
    int hw = m0 + m;
    if (hw < HW) {
      uint4 v = *(const uint4*)(lds + m * 256 + (((e & 15) * 16) ^ ((m & 15) << 4)));
      *(uint4*)(h1t + ((size_t)n * HW + hw) * CH + (e & 15) * 8) = v;
    }
  }
}

// ---------------------------------------------------------------------------
// dht (gather) — unchanged from R4
// ---------------------------------------------------------------------------
__global__ void __launch_bounds__(1024)
k_dht(const u16* __restrict__ h1t, const u16* __restrict__ list,
      const int* __restrict__ coff, u16* __restrict__ dht) {
  __shared__ int soff[NR + 1];
  int id = blockIdx.x;
  int x  = id & 7;
  int l  = id >> 3;
  int n  = (x << 1) | (l >= 100 ? 1 : 0);
  int a  = (l >= 100) ? l - 100 : l;
  int t  = threadIdx.x;
  int c  = t & 63;
  int w  = t >> 6;

  if (t <= NR) soff[t] = coff[a * (NR + 1) + t];
  __syncthreads();

  const unsigned int* img = (const unsigned int*)(h1t + (size_t)n * HW * CH) + c;
  const u16* lst = list + (size_t)a * HW;
  unsigned int* out32 = (unsigned int*)(dht + ((size_t)(n * NA + a) * NR) * CH) + c;

  for (int r = 0; r < NR; ++r) {
    int o0 = soff[r], o1 = soff[r + 1];
    int owner = (o0 + ((o1 - o0) >> 1)) * 16 / HW;
    owner = owner > 15 ? 15 : owner;
    if (owner != w) continue;
    float ax = 0.f, ay = 0.f;
#pragma unroll 4
    for (int k = o0; k < o1; ++k) {
      int p = (int)lst[k];
      unsigned int v = img[(size_t)p << 6];
      ax += bf2f((u16)(v & 0xffffu));
      ay += bf2f((u16)(v >> 16));
    }
    unsigned int pk = (unsigned int)f2bf(ax) | ((unsigned int)f2bf(ay) << 16);
    out32[(size_t)r << 6] = pk;
  }
}

// ---------------------------------------------------------------------------
// conv3x3 (MFMA implicit GEMM): X[N][A][R][CH] bf16, 3x3 zero-pad conv + BN + ReLU.
// Block 256 thr = 4 waves (2x2). Spatial tile 16a x 8r (M=128), N=128 co.
// A halo (18x10x128) staged once in swizzled LDS; B frags from global (L2).
// OUT_MODE 0: bf16 [N][A][R][CH] via LDS transpose; 1: f32 [N][CH][A][R] float4.
// ---------------------------------------------------------------------------
template <int OUT_MODE>
__global__ void __launch_bounds__(256)
k_conv3x3(const u16* __restrict__ X, const u16* __restrict__ wbf,
          const float* __restrict__ pb, const float* __restrict__ pg,
          const float* __restrict__ pbe, void* __restrict__ out) {
  __shared__ uint4 lds4[2880];               // 46080 B: 180 rows x 256B swizzled
  char* lds = (char*)lds4;
  int n    = blockIdx.y;
  int tile = blockIdx.x;                     // 0..90
  int ta = tile / 13, tr = tile - ta * 13;
  int a0 = ta * 16, r0 = tr * 8;
  int t  = threadIdx.x;
  int l  = t & 63, w = t >> 6, wm = w >> 1, wn = w & 1;

  {                                          // stage halo
    int sr16 = t >> 4;
    int cb   = (t & 15) * 16;
#pragma unroll
    for (int p = 0; p < 12; ++p) {
      int s = p * 16 + sr16;
      if (s < 180) {
        int sa = a0 - 1 + s / 10;
        int sr = r0 - 1 + s % 10;
        uint4 v = make_uint4(0, 0, 0, 0);
        if (sa >= 0 && sa < NA && sr >= 0 && sr < NR)
          v = *(const uint4*)(X + ((size_t)(n * NA + sa) * NR + sr) * CH + (t & 15) * 8);
        *(uint4*)(lds + s * 256 + (cb ^ ((s & 15) << 4))) = v;
      }
    }
  }
  __syncthreads();

  int sbase[4];
#pragma unroll
  for (int fm = 0; fm < 4; ++fm) {
    int m = wm * 64 + fm * 16 + (l & 15);
    sbase[fm] = ((m >> 3) + 1) * 10 + (m & 7) + 1;
  }
  int kseg = (l >> 4) * 16;

  f32x4 acc[4][4];
  f32x4 zf = {0.f, 0.f, 0.f, 0.f};
#pragma unroll
  for (int i = 0; i < 4; ++i)
#pragma unroll
    for (int j = 0; j < 4; ++j) acc[i][j] = zf;

  for (int tap = 0; tap < 9; ++tap) {
    int soff = (tap / 3 - 1) * 10 + (tap % 3 - 1);
#pragma unroll
    for (int kc = 0; kc < 4; ++kc) {
      short8 afr[4], bfr[4];
#pragma unroll
      for (int fm = 0; fm < 4; ++fm) {
        int s = sbase[fm] + soff;
        afr[fm] = *(const short8*)(lds + s * 256 + ((kc * 64 + kseg) ^ ((s & 15) << 4)));
      }
#pragma unroll
      for (int fn = 0; fn < 4; ++fn)
        bfr[fn] = *(const short8*)(wbf + (((size_t)(tap * 4 + kc) * 8 + wn * 4 + fn) * 64 + l) * 8);
#pragma unroll
      for (int fm = 0; fm < 4; ++fm)
#pragma unroll
        for (int fn = 0; fn < 4; ++fn)
          acc[fm][fn] = __builtin_amdgcn_mfma_f32_16x16x32_bf16(afr[fm], bfr[fn], acc[fm][fn], 0, 0, 0);
    }
  }

  float sc[4], sh[4];
#pragma unroll
  for (int fn = 0; fn < 4; ++fn) {
    int co = wn * 64 + fn * 16 + (l & 15);
    float s = pg[co] / sqrtf(1.f + 1e-5f);
    sc[fn] = s;
    sh[fn] = pb[co] * s + pbe[co];
  }

  if (OUT_MODE == 0) {
    __syncthreads();
#pragma unroll
    for (int fm = 0; fm < 4; ++fm)
#pragma unroll
      for (int fn = 0; fn < 4; ++fn) {
        int co = wn * 64 + fn * 16 + (l & 15);
#pragma unroll
        for (int q = 0; q < 4; ++q) {
          int m = wm * 64 + fm * 16 + (l >> 4) * 4 + q;
          float y = fmaxf(acc[fm][fn][q] * sc[fn] + sh[fn], 0.f);
          *(u16*)(lds + m * 256 + ((co * 2) ^ ((m & 15) << 4))) = f2bf(y);
        }
      }
    __syncthreads();
    u16* o = (u16*)out;
#pragma unroll
    for (int p = 0; p < 8; ++p) {
      int e = p * 256 + t;
      int m = e >> 4;
      int a = a0 + (m >> 3), r = r0 + (m & 7);
      if (a < NA && r < NR) {
        uint4 v = *(const uint4*)(lds + m * 256 + (((e & 15) * 16) ^ ((m & 15) << 4)));
        *(uint4*)(o + ((size_t)(n * NA + a) * NR + r) * CH + (e & 15) * 8) = v;
      }
    }
  } else {
    float* o = (float*)out;
#pragma unroll
    for (int fm = 0; fm < 4; ++fm) {
      int mb = wm * 64 + fm * 16 + (l >> 4) * 4;
      int a  = a0 + (mb >> 3), rr = r0 + (mb & 7);
      if (a < NA && rr < NR) {
#pragma unroll
        for (int fn = 0; fn < 4; ++fn) {
          int co = wn * 64 + fn * 16 + (l & 15);
          float4 v;
          v.x = fmaxf(acc[fm][fn][0] * sc[fn] + sh[fn], 0.f);
          v.y = fmaxf(acc[fm][fn][1] * sc[fn] + sh[fn], 0.f);
          v.z = fmaxf(acc[fm][fn][2] * sc[fn] + sh[fn], 0.f);
          v.w = fmaxf(acc[fm][fn][3] * sc[fn] + sh[fn], 0.f);
          *(float4*)(o + ((size_t)n * CH + co) * HW + a * NR + rr) = v;
        }
      }
    }
  }
}

// ---------------------------------------------------------------------------
extern "C" void kernel_launch(void* const* d_in, const int* in_sizes, int n_in,
                              void* d_out, int out_size, void* d_ws, size_t ws_size,
                              hipStream_t stream) {
  if (n_in < 13) return;
  const float* x   = (const float*)d_in[0];
  const float* w1  = (const float*)d_in[1];
  const float* b1  = (const float*)d_in[2];
  const float* g1  = (const float*)d_in[3];
  const float* be1 = (const float*)d_in[4];
  const float* w2  = (const float*)d_in[5];
  const float* b2  = (const float*)d_in[6];
  const float* g2  = (const float*)d_in[7];
  const float* be2 = (const float*)d_in[8];
  const float* w3  = (const float*)d_in[9];
  const float* b3  = (const float*)d_in[10];
  const float* g3  = (const float*)d_in[11];
  const float* be3 = (const float*)d_in[12];

  // workspace layout (256B-aligned)
  const size_t o_list = 0;                    // u16[100][10000]      = 2,000,000
  const size_t o_coff = 2000128;              // int[100][101]        =    40,400
  const size_t o_wbf1 = 2040576;              // u16[32768]           =    65,536
  const size_t o_wbf2 = o_wbf1 + 65536;       // u16[147456]          =   294,912
  const size_t o_wbf3 = o_wbf2 + 294912;      // u16[147456]          =   294,912
  const size_t o_dht  = o_wbf3 + 294912;      // 40,960,000 (xt overlays dht+c2: 81,920,000)
  const size_t o_c2   = o_dht + 40960000;     // 40,960,000
  const size_t need   = o_dht + 81920000;     // ~84.6 MB
  if (ws_size < need) return;

  char*  ws   = (char*)d_ws;
  u16*   list = (u16*)(ws + o_list);
  int*   coff = (int*)(ws + o_coff);
  u16*   wbf1 = (u16*)(ws + o_wbf1);
  u16*   wbf2 = (u16*)(ws + o_wbf2);
  u16*   wbf3 = (u16*)(ws + o_wbf3);
  u16*   xt   = (u16*)(ws + o_dht);   // dead after k_conv1
  u16*   dht  = (u16*)(ws + o_dht);   // written by k_dht after xt is dead
  u16*   c2   = (u16*)(ws + o_c2);
  u16*   h1t  = (u16*)d_out;          // bf16 scratch inside f32 out (dead before conv3)

  k_prep<<<dim3(576), dim3(256), 0, stream>>>(w1, w2, w3, wbf1, wbf2, wbf3);
  k_csr<<<dim3(100), dim3(256), 0, stream>>>(list, coff);
  k_xt<<<dim3(157, 4, 16), dim3(256), 0, stream>>>(x, xt);
  k_conv1<<<dim3(79, 16), dim3(256), 0, stream>>>(xt, wbf1, b1, g1, be1, h1t);
  k_dht<<<dim3(1600), dim3(1024), 0, stream>>>(h1t, list, coff, dht);
  k_conv3x3<0><<<dim3(91, 16), dim3(256), 0, stream>>>(dht, wbf2, b2, g2, be2, (void*)c2);
  k_conv3x3<1><<<dim3(91, 16), dim3(256), 0, stream>>>(c2, wbf3, b3, g3, be3, d_out);
}

// Round 7
// 696.019 us; speedup vs baseline: 11.6035x; 1.8528x over previous
//
#include <hip/hip_runtime.h>
#include <hip/hip_bf16.h>
#include <math.h>

#ifndef M_PI
#define M_PI 3.14159265358979323846
#endif

typedef unsigned short u16;
typedef short short8 __attribute__((ext_vector_type(8)));
typedef float f32x4 __attribute__((ext_vector_type(4)));

#define CIN  256
#define CH   128
#define HW   10000
#define NA   100
#define NR   100

__device__ __forceinline__ float bf2f(u16 v) {
  return __uint_as_float(((unsigned int)v) << 16);
}
__device__ __forceinline__ u16 f2bf(float f) {
  unsigned int u = __float_as_uint(f);
  u += 0x7fffu + ((u >> 16) & 1u);   // round-to-nearest-even
  return (u16)(u >> 16);
}

// ---------------------------------------------------------------------------
// prep: fragment-ready bf16 weights. (unchanged)
// ---------------------------------------------------------------------------
__global__ void k_prep(const float* __restrict__ w1, const float* __restrict__ w2,
                       const float* __restrict__ w3, u16* __restrict__ wbf1,
                       u16* __restrict__ wbf2, u16* __restrict__ wbf3) {
  int t = blockIdx.x * blockDim.x + threadIdx.x;
  if (t < 32768) {
    int j = t & 7, lp = (t >> 3) & 63, nf = (t >> 9) & 7, kc = t >> 12;
    int co = nf * 16 + (lp & 15);
    int ci = kc * 32 + (lp >> 4) * 8 + j;
    wbf1[t] = f2bf(w1[co * CIN + ci]);
  }
  if (t < 147456) {
    int j = t & 7, lp = (t >> 3) & 63, nf = (t >> 9) & 7, kc = (t >> 12) & 3, tap = t >> 14;
    int co = nf * 16 + (lp & 15);
    int ci = kc * 32 + (lp >> 4) * 8 + j;
    wbf2[t] = f2bf(w2[(co * CH + ci) * 9 + tap]);
    wbf3[t] = f2bf(w3[(co * CH + ci) * 9 + tap]);
  }
}

// ---------------------------------------------------------------------------
// csr v2b: parallel stable counting sort. Block = angle.
// Phase 1: thread t bins row t (100 px), counts rowcnt[t][bin].
// Phase 2: thread b prefixes rowcnt[.][b] over rows; thread 0 scans bin totals.
// Phase 3: thread t scatters row t: pos = off[r] + rowcnt[t][r]++ (stable).
// FIX vs R5: zero ALL 100 u16 (50 u32) of rowcnt[t] — 25 left half garbage.
// ---------------------------------------------------------------------------
__global__ void __launch_bounds__(256)
k_csr(u16* __restrict__ list, int* __restrict__ coff) {
#pragma clang fp contract(off)
  __shared__ unsigned char sidx[HW];            // 10000 B
  __shared__ unsigned short rowcnt[100][100];   // 20000 B: count -> exclusive prefix
  __shared__ int off[NR + 1];
  int a = blockIdx.x;
  int t = threadIdx.x;

  double theta = (double)a * (M_PI / 100.0);
  double irho  = 142.0 / 99.0;   // (floor(sqrt(2*100^2))+1)/(numRho-1)
  double ct = cos(theta) / irho;
  double st = sin(theta) / irho;

  if (t < 100) {
    for (int b = 0; b < 50; ++b) ((unsigned int*)&rowcnt[t][0])[b] = 0;   // zero 100 u16 = 50 u32
    int base = t * 100;
    for (int j = 0; j < 100; ++j) {
      double s = (double)(j - 50) * ct + (double)(t - 50) * st;
      int r = (int)rint(s) + 50;
      r = r < 0 ? 0 : (r > 99 ? 99 : r);
      sidx[base + j] = (unsigned char)r;
      rowcnt[t][r]++;
    }
  }
  __syncthreads();

  if (t < 100) {            // column prefix for bin t over rows
    int running = 0;
    for (int c = 0; c < 100; ++c) {
      int tmp = rowcnt[c][t];
      rowcnt[c][t] = (unsigned short)running;
      running += tmp;
    }
    off[t + 1] = running;   // bin t total (scanned below)
  }
  __syncthreads();

  if (t == 0) {
    off[0] = 0;
    for (int b = 0; b < NR; ++b) {
      int cb = off[b + 1];
      off[b + 1] = off[b] + cb;
    }
  }
  __syncthreads();
  if (t <= NR) coff[a * (NR + 1) + t] = off[t];

  if (t < 100) {
    u16* dst = list + (size_t)a * HW;
    int base = t * 100;
    for (int j = 0; j < 100; ++j) {
      int r = sidx[base + j];
      int pos = off[r] + rowcnt[t][r];
      rowcnt[t][r]++;
      dst[pos] = (u16)(base + j);
    }
  }
}

// ---------------------------------------------------------------------------
// xt: transpose+cast x[N][CIN][HW] f32 -> xt[N][HW][CIN] bf16 (unchanged)
// ---------------------------------------------------------------------------
__global__ void __launch_bounds__(256)
k_xt(const float* __restrict__ x, u16* __restrict__ xt) {
  __shared__ u16 tl[64][70];
  int n = blockIdx.z, c0 = blockIdx.y * 64, h0 = blockIdx.x * 64;
  int t = threadIdx.x;
#pragma unroll
  for (int p = 0; p < 16; ++p) {
    int row = p * 4 + (t >> 6);
    int col = t & 63;
    int hw  = h0 + col;
    float v = (hw < HW) ? x[((size_t)n * CIN + c0 + row) * HW + hw] : 0.f;
    tl[row][col] = f2bf(v);
  }
  __syncthreads();
  int hr = t >> 2;
  int sc = (t & 3) * 16;
  int hw = h0 + hr;
  if (hw < HW) {
    u16 vals[16];
#pragma unroll
    for (int j = 0; j < 16; ++j) vals[j] = tl[sc + j][hr];
    u16* dst = xt + ((size_t)n * HW + hw) * CIN + c0 + sc;
    *(uint4*)(dst)     = *(uint4*)&vals[0];
    *(uint4*)(dst + 8) = *(uint4*)&vals[8];
  }
}

// ---------------------------------------------------------------------------
// conv1 (MFMA GEMM) — unchanged
// ---------------------------------------------------------------------------
__global__ void __launch_bounds__(256)
k_conv1(const u16* __restrict__ xt, const u16* __restrict__ wbf1,
        const float* __restrict__ pb, const float* __restrict__ pg,
        const float* __restrict__ pbe, u16* __restrict__ h1t) {
  __shared__ uint4 lds4[4096];
  char* lds = (char*)lds4;
  int n  = blockIdx.y;
  int m0 = blockIdx.x * 128;
  int t  = threadIdx.x;
  int l  = t & 63, w = t >> 6, wm = w >> 1, wn = w & 1;

  {
    int r8  = t >> 5;
    int seg = t & 31;
#pragma unroll
    for (int p = 0; p < 16; ++p) {
      int m  = p * 8 + r8;
      int hw = m0 + m;
      uint4 v = make_uint4(0, 0, 0, 0);
      if (hw < HW) v = *(const uint4*)(xt + ((size_t)n * HW + hw) * CIN + seg * 8);
      *(uint4*)(lds + m * 512 + ((seg * 16) ^ ((m & 31) << 4))) = v;
    }
  }
  __syncthreads();

  int kseg = (l >> 4) * 16;
  f32x4 acc[4][4];
  f32x4 zf = {0.f, 0.f, 0.f, 0.f};
#pragma unroll
  for (int i = 0; i < 4; ++i)
#pragma unroll
    for (int j = 0; j < 4; ++j) acc[i][j] = zf;

  for (int kc = 0; kc < 8; ++kc) {
    short8 afr[4], bfr[4];
#pragma unroll
    for (int fm = 0; fm < 4; ++fm) {
      int m = wm * 64 + fm * 16 + (l & 15);
      afr[fm] = *(const short8*)(lds + m * 512 + ((kc * 64 + kseg) ^ ((m & 31) << 4)));
    }
#pragma unroll
    for (int fn = 0; fn < 4; ++fn)
      bfr[fn] = *(const short8*)(wbf1 + (((size_t)kc * 8 + wn * 4 + fn) * 64 + l) * 8);
#pragma unroll
    for (int fm = 0; fm < 4; ++fm)
#pragma unroll
      for (int fn = 0; fn < 4; ++fn)
        acc[fm][fn] = __builtin_amdgcn_mfma_f32_16x16x32_bf16(afr[fm], bfr[fn], acc[fm][fn], 0, 0, 0);
  }

  float sc[4], sh[4];
#pragma unroll
  for (int fn = 0; fn < 4; ++fn) {
    int co = wn * 64 + fn * 16 + (l & 15);
    float s = pg[co] / sqrtf(1.f + 1e-5f);
    sc[fn] = s;
    sh[fn] = pb[co] * s + pbe[co];
  }

  __syncthreads();
#pragma unroll
  for (int fm = 0; fm < 4; ++fm)
#pragma unroll
    for (int fn = 0; fn < 4; ++fn) {
      int co = wn * 64 + fn * 16 + (l & 15);
#pragma unroll
      for (int q = 0; q < 4; ++q) {
        int m = wm * 64 + fm * 16 + (l >> 4) * 4 + q;
        float y = fmaxf(acc[fm][fn][q] * sc[fn] + sh[fn], 0.f);
        *(u16*)(lds + m * 256 + ((co * 2) ^ ((m & 15) << 4))) = f2bf(y);
      }
    }
  __syncthreads();
#pragma unroll
  for (int p = 0; p < 8; ++p) {
    int e = p * 256 + t;
    int m = e >> 4;
    int hw = m0 + m;
    if (hw < HW) {
      uint4 v = *(const uint4*)(lds + m * 256 + (((e & 15) * 16) ^ ((m & 15) << 4)));
      *(uint4*)(h1t + ((size_t)n * HW + hw) * CH + (e & 15) * 8) = v;
    }
  }
}

// ---------------------------------------------------------------------------
// dht (gather) — unchanged
// ---------------------------------------------------------------------------
__global__ void __launch_bounds__(1024)
k_dht(const u16* __restrict__ h1t, const u16* __restrict__ list,
      const int* __restrict__ coff, u16* __restrict__ dht) {
  __shared__ int soff[NR + 1];
  int id = blockIdx.x;
  int x  = id & 7;
  int l  = id >> 3;
  int n  = (x << 1) | (l >= 100 ? 1 : 0);
  int a  = (l >= 100) ? l - 100 : l;
  int t  = threadIdx.x;
  int c  = t & 63;
  int w  = t >> 6;

  if (t <= NR) soff[t] = coff[a * (NR + 1) + t];
  __syncthreads();

  const unsigned int* img = (const unsigned int*)(h1t + (size_t)n * HW * CH) + c;
  const u16* lst = list + (size_t)a * HW;
  unsigned int* out32 = (unsigned int*)(dht + ((size_t)(n * NA + a) * NR) * CH) + c;

  for (int r = 0; r < NR; ++r) {
    int o0 = soff[r], o1 = soff[r + 1];
    int owner = (o0 + ((o1 - o0) >> 1)) * 16 / HW;
    owner = owner > 15 ? 15 : owner;
    if (owner != w) continue;
    float ax = 0.f, ay = 0.f;
#pragma unroll 4
    for (int k = o0; k < o1; ++k) {
      int p = (int)lst[k];
      unsigned int v = img[(size_t)p << 6];
      ax += bf2f((u16)(v & 0xffffu));
      ay += bf2f((u16)(v >> 16));
    }
    unsigned int pk = (unsigned int)f2bf(ax) | ((unsigned int)f2bf(ay) << 16);
    out32[(size_t)r << 6] = pk;
  }
}

// ---------------------------------------------------------------------------
// conv3x3 (MFMA implicit GEMM) — unchanged
// ---------------------------------------------------------------------------
template <int OUT_MODE>
__global__ void __launch_bounds__(256)
k_conv3x3(const u16* __restrict__ X, const u16* __restrict__ wbf,
          const float* __restrict__ pb, const float* __restrict__ pg,
          const float* __restrict__ pbe, void* __restrict__ out) {
  __shared__ uint4 lds4[2880];
  char* lds = (char*)lds4;
  int n    = blockIdx.y;
  int tile = blockIdx.x;
  int ta = tile / 13, tr = tile - ta * 13;
  int a0 = ta * 16, r0 = tr * 8;
  int t  = threadIdx.x;
  int l  = t & 63, w = t >> 6, wm = w >> 1, wn = w & 1;

  {
    int sr16 = t >> 4;
    int cb   = (t & 15) * 16;
#pragma unroll
    for (int p = 0; p < 12; ++p) {
      int s = p * 16 + sr16;
      if (s < 180) {
        int sa = a0 - 1 + s / 10;
        int sr = r0 - 1 + s % 10;
        uint4 v = make_uint4(0, 0, 0, 0);
        if (sa >= 0 && sa < NA && sr >= 0 && sr < NR)
          v = *(const uint4*)(X + ((size_t)(n * NA + sa) * NR + sr) * CH + (t & 15) * 8);
        *(uint4*)(lds + s * 256 + (cb ^ ((s & 15) << 4))) = v;
      }
    }
  }
  __syncthreads();

  int sbase[4];
#pragma unroll
  for (int fm = 0; fm < 4; ++fm) {
    int m = wm * 64 + fm * 16 + (l & 15);
    sbase[fm] = ((m >> 3) + 1) * 10 + (m & 7) + 1;
  }
  int kseg = (l >> 4) * 16;

  f32x4 acc[4][4];
  f32x4 zf = {0.f, 0.f, 0.f, 0.f};
#pragma unroll
  for (int i = 0; i < 4; ++i)
#pragma unroll
    for (int j = 0; j < 4; ++j) acc[i][j] = zf;

  for (int tap = 0; tap < 9; ++tap) {
    int soff = (tap / 3 - 1) * 10 + (tap % 3 - 1);
#pragma unroll
    for (int kc = 0; kc < 4; ++kc) {
      short8 afr[4], bfr[4];
#pragma unroll
      for (int fm = 0; fm < 4; ++fm) {
        int s = sbase[fm] + soff;
        afr[fm] = *(const short8*)(lds + s * 256 + ((kc * 64 + kseg) ^ ((s & 15) << 4)));
      }
#pragma unroll
      for (int fn = 0; fn < 4; ++fn)
        bfr[fn] = *(const short8*)(wbf + (((size_t)(tap * 4 + kc) * 8 + wn * 4 + fn) * 64 + l) * 8);
#pragma unroll
      for (int fm = 0; fm < 4; ++fm)
#pragma unroll
        for (int fn = 0; fn < 4; ++fn)
          acc[fm][fn] = __builtin_amdgcn_mfma_f32_16x16x32_bf16(afr[fm], bfr[fn], acc[fm][fn], 0, 0, 0);
    }
  }

  float sc[4], sh[4];
#pragma unroll
  for (int fn = 0; fn < 4; ++fn) {
    int co = wn * 64 + fn * 16 + (l & 15);
    float s = pg[co] / sqrtf(1.f + 1e-5f);
    sc[fn] = s;
    sh[fn] = pb[co] * s + pbe[co];
  }

  if (OUT_MODE == 0) {
    __syncthreads();
#pragma unroll
    for (int fm = 0; fm < 4; ++fm)
#pragma unroll
      for (int fn = 0; fn < 4; ++fn) {
        int co = wn * 64 + fn * 16 + (l & 15);
#pragma unroll
        for (int q = 0; q < 4; ++q) {
          int m = wm * 64 + fm * 16 + (l >> 4) * 4 + q;
          float y = fmaxf(acc[fm][fn][q] * sc[fn] + sh[fn], 0.f);
          *(u16*)(lds + m * 256 + ((co * 2) ^ ((m & 15) << 4))) = f2bf(y);
        }
      }
    __syncthreads();
    u16* o = (u16*)out;
#pragma unroll
    for (int p = 0; p < 8; ++p) {
      int e = p * 256 + t;
      int m = e >> 4;
      int a = a0 + (m >> 3), r = r0 + (m & 7);
      if (a < NA && r < NR) {
        uint4 v = *(const uint4*)(lds + m * 256 + (((e & 15) * 16) ^ ((m & 15) << 4)));
        *(uint4*)(o + ((size_t)(n * NA + a) * NR + r) * CH + (e & 15) * 8) = v;
      }
    }
  } else {
    float* o = (float*)out;
#pragma unroll
    for (int fm = 0; fm < 4; ++fm) {
      int mb = wm * 64 + fm * 16 + (l >> 4) * 4;
      int a  = a0 + (mb >> 3), rr = r0 + (mb & 7);
      if (a < NA && rr < NR) {
#pragma unroll
        for (int fn = 0; fn < 4; ++fn) {
          int co = wn * 64 + fn * 16 + (l & 15);
          float4 v;
          v.x = fmaxf(acc[fm][fn][0] * sc[fn] + sh[fn], 0.f);
          v.y = fmaxf(acc[fm][fn][1] * sc[fn] + sh[fn], 0.f);
          v.z = fmaxf(acc[fm][fn][2] * sc[fn] + sh[fn], 0.f);
          v.w = fmaxf(acc[fm][fn][3] * sc[fn] + sh[fn], 0.f);
          *(float4*)(o + ((size_t)n * CH + co) * HW + a * NR + rr) = v;
        }
      }
    }
  }
}

// ---------------------------------------------------------------------------
extern "C" void kernel_launch(void* const* d_in, const int* in_sizes, int n_in,
                              void* d_out, int out_size, void* d_ws, size_t ws_size,
                              hipStream_t stream) {
  if (n_in < 13) return;
  const float* x   = (const float*)d_in[0];
  const float* w1  = (const float*)d_in[1];
  const float* b1  = (const float*)d_in[2];
  const float* g1  = (const float*)d_in[3];
  const float* be1 = (const float*)d_in[4];
  const float* w2  = (const float*)d_in[5];
  const float* b2  = (const float*)d_in[6];
  const float* g2  = (const float*)d_in[7];
  const float* be2 = (const float*)d_in[8];
  const float* w3  = (const float*)d_in[9];
  const float* b3  = (const float*)d_in[10];
  const float* g3  = (const float*)d_in[11];
  const float* be3 = (const float*)d_in[12];

  // workspace layout (256B-aligned)
  const size_t o_list = 0;                    // u16[100][10000]      = 2,000,000
  const size_t o_coff = 2000128;              // int[100][101]        =    40,400
  const size_t o_wbf1 = 2040576;              // u16[32768]           =    65,536
  const size_t o_wbf2 = o_wbf1 + 65536;       // u16[147456]          =   294,912
  const size_t o_wbf3 = o_wbf2 + 294912;      // u16[147456]          =   294,912
  const size_t o_dht  = o_wbf3 + 294912;      // 40,960,000 (xt overlays dht+c2: 81,920,000)
  const size_t o_c2   = o_dht + 40960000;     // 40,960,000
  const size_t need   = o_dht + 81920000;     // ~84.6 MB
  if (ws_size < need) return;

  char*  ws   = (char*)d_ws;
  u16*   list = (u16*)(ws + o_list);
  int*   coff = (int*)(ws + o_coff);
  u16*   wbf1 = (u16*)(ws + o_wbf1);
  u16*   wbf2 = (u16*)(ws + o_wbf2);
  u16*   wbf3 = (u16*)(ws + o_wbf3);
  u16*   xt   = (u16*)(ws + o_dht);   // dead after k_conv1
  u16*   dht  = (u16*)(ws + o_dht);   // written by k_dht after xt is dead
  u16*   c2   = (u16*)(ws + o_c2);
  u16*   h1t  = (u16*)d_out;          // bf16 scratch inside f32 out (dead before conv3)

  k_prep<<<dim3(576), dim3(256), 0, stream>>>(w1, w2, w3, wbf1, wbf2, wbf3);
  k_csr<<<dim3(100), dim3(256), 0, stream>>>(list, coff);
  k_xt<<<dim3(157, 4, 16), dim3(256), 0, stream>>>(x, xt);
  k_conv1<<<dim3(79, 16), dim3(256), 0, stream>>>(xt, wbf1, b1, g1, be1, h1t);
  k_dht<<<dim3(1600), dim3(1024), 0, stream>>>(h1t, list, coff, dht);
  k_conv3x3<0><<<dim3(91, 16), dim3(256), 0, stream>>>(dht, wbf2, b2, g2, be2, (void*)c2);
  k_conv3x3<1><<<dim3(91, 16), dim3(256), 0, stream>>>(c2, wbf3, b3, g3, be3, d_out);
}

// Round 8
// 580.357 us; speedup vs baseline: 13.9160x; 1.1993x over previous
//
#include <hip/hip_runtime.h>
#include <hip/hip_bf16.h>
#include <math.h>

#ifndef M_PI
#define M_PI 3.14159265358979323846
#endif

typedef unsigned short u16;
typedef short short8 __attribute__((ext_vector_type(8)));
typedef float f32x4 __attribute__((ext_vector_type(4)));

#define CIN  256
#define CH   128
#define HW   10000
#define NA   100
#define NR   100

__device__ __forceinline__ float bf2f(u16 v) {
  return __uint_as_float(((unsigned int)v) << 16);
}
__device__ __forceinline__ u16 f2bf(float f) {
  unsigned int u = __float_as_uint(f);
  u += 0x7fffu + ((u >> 16) & 1u);   // round-to-nearest-even
  return (u16)(u >> 16);
}

// ---------------------------------------------------------------------------
// prep: fragment-ready bf16 weights. (unchanged)
// ---------------------------------------------------------------------------
__global__ void k_prep(const float* __restrict__ w1, const float* __restrict__ w2,
                       const float* __restrict__ w3, u16* __restrict__ wbf1,
                       u16* __restrict__ wbf2, u16* __restrict__ wbf3) {
  int t = blockIdx.x * blockDim.x + threadIdx.x;
  if (t < 32768) {
    int j = t & 7, lp = (t >> 3) & 63, nf = (t >> 9) & 7, kc = t >> 12;
    int co = nf * 16 + (lp & 15);
    int ci = kc * 32 + (lp >> 4) * 8 + j;
    wbf1[t] = f2bf(w1[co * CIN + ci]);
  }
  if (t < 147456) {
    int j = t & 7, lp = (t >> 3) & 63, nf = (t >> 9) & 7, kc = (t >> 12) & 3, tap = t >> 14;
    int co = nf * 16 + (lp & 15);
    int ci = kc * 32 + (lp >> 4) * 8 + j;
    wbf2[t] = f2bf(w2[(co * CH + ci) * 9 + tap]);
    wbf3[t] = f2bf(w3[(co * CH + ci) * 9 + tap]);
  }
}

// ---------------------------------------------------------------------------
// csr v2b: parallel stable counting sort. (unchanged)
// ---------------------------------------------------------------------------
__global__ void __launch_bounds__(256)
k_csr(u16* __restrict__ list, int* __restrict__ coff) {
#pragma clang fp contract(off)
  __shared__ unsigned char sidx[HW];            // 10000 B
  __shared__ unsigned short rowcnt[100][100];   // 20000 B
  __shared__ int off[NR + 1];
  int a = blockIdx.x;
  int t = threadIdx.x;

  double theta = (double)a * (M_PI / 100.0);
  double irho  = 142.0 / 99.0;   // (floor(sqrt(2*100^2))+1)/(numRho-1)
  double ct = cos(theta) / irho;
  double st = sin(theta) / irho;

  if (t < 100) {
    for (int b = 0; b < 50; ++b) ((unsigned int*)&rowcnt[t][0])[b] = 0;
    int base = t * 100;
    for (int j = 0; j < 100; ++j) {
      double s = (double)(j - 50) * ct + (double)(t - 50) * st;
      int r = (int)rint(s) + 50;
      r = r < 0 ? 0 : (r > 99 ? 99 : r);
      sidx[base + j] = (unsigned char)r;
      rowcnt[t][r]++;
    }
  }
  __syncthreads();

  if (t < 100) {
    int running = 0;
    for (int c = 0; c < 100; ++c) {
      int tmp = rowcnt[c][t];
      rowcnt[c][t] = (unsigned short)running;
      running += tmp;
    }
    off[t + 1] = running;
  }
  __syncthreads();

  if (t == 0) {
    off[0] = 0;
    for (int b = 0; b < NR; ++b) {
      int cb = off[b + 1];
      off[b + 1] = off[b] + cb;
    }
  }
  __syncthreads();
  if (t <= NR) coff[a * (NR + 1) + t] = off[t];

  if (t < 100) {
    u16* dst = list + (size_t)a * HW;
    int base = t * 100;
    for (int j = 0; j < 100; ++j) {
      int r = sidx[base + j];
      int pos = off[r] + rowcnt[t][r];
      rowcnt[t][r]++;
      dst[pos] = (u16)(base + j);
    }
  }
}

// ---------------------------------------------------------------------------
// xt: transpose+cast x[N][CIN][HW] f32 -> xt[N][HW][CIN] bf16 (unchanged)
// ---------------------------------------------------------------------------
__global__ void __launch_bounds__(256)
k_xt(const float* __restrict__ x, u16* __restrict__ xt) {
  __shared__ u16 tl[64][70];
  int n = blockIdx.z, c0 = blockIdx.y * 64, h0 = blockIdx.x * 64;
  int t = threadIdx.x;
#pragma unroll
  for (int p = 0; p < 16; ++p) {
    int row = p * 4 + (t >> 6);
    int col = t & 63;
    int hw  = h0 + col;
    float v = (hw < HW) ? x[((size_t)n * CIN + c0 + row) * HW + hw] : 0.f;
    tl[row][col] = f2bf(v);
  }
  __syncthreads();
  int hr = t >> 2;
  int sc = (t & 3) * 16;
  int hw = h0 + hr;
  if (hw < HW) {
    u16 vals[16];
#pragma unroll
    for (int j = 0; j < 16; ++j) vals[j] = tl[sc + j][hr];
    u16* dst = xt + ((size_t)n * HW + hw) * CIN + c0 + sc;
    *(uint4*)(dst)     = *(uint4*)&vals[0];
    *(uint4*)(dst + 8) = *(uint4*)&vals[8];
  }
}

// ---------------------------------------------------------------------------
// conv1 (MFMA GEMM) — unchanged
// ---------------------------------------------------------------------------
__global__ void __launch_bounds__(256)
k_conv1(const u16* __restrict__ xt, const u16* __restrict__ wbf1,
        const float* __restrict__ pb, const float* __restrict__ pg,
        const float* __restrict__ pbe, u16* __restrict__ h1t) {
  __shared__ uint4 lds4[4096];
  char* lds = (char*)lds4;
  int n  = blockIdx.y;
  int m0 = blockIdx.x * 128;
  int t  = threadIdx.x;
  int l  = t & 63, w = t >> 6, wm = w >> 1, wn = w & 1;

  {
    int r8  = t >> 5;
    int seg = t & 31;
#pragma unroll
    for (int p = 0; p < 16; ++p) {
      int m  = p * 8 + r8;
      int hw = m0 + m;
      uint4 v = make_uint4(0, 0, 0, 0);
      if (hw < HW) v = *(const uint4*)(xt + ((size_t)n * HW + hw) * CIN + seg * 8);
      *(uint4*)(lds + m * 512 + ((seg * 16) ^ ((m & 31) << 4))) = v;
    }
  }
  __syncthreads();

  int kseg = (l >> 4) * 16;
  f32x4 acc[4][4];
  f32x4 zf = {0.f, 0.f, 0.f, 0.f};
#pragma unroll
  for (int i = 0; i < 4; ++i)
#pragma unroll
    for (int j = 0; j < 4; ++j) acc[i][j] = zf;

  for (int kc = 0; kc < 8; ++kc) {
    short8 afr[4], bfr[4];
#pragma unroll
    for (int fm = 0; fm < 4; ++fm) {
      int m = wm * 64 + fm * 16 + (l & 15);
      afr[fm] = *(const short8*)(lds + m * 512 + ((kc * 64 + kseg) ^ ((m & 31) << 4)));
    }
#pragma unroll
    for (int fn = 0; fn < 4; ++fn)
      bfr[fn] = *(const short8*)(wbf1 + (((size_t)kc * 8 + wn * 4 + fn) * 64 + l) * 8);
#pragma unroll
    for (int fm = 0; fm < 4; ++fm)
#pragma unroll
      for (int fn = 0; fn < 4; ++fn)
        acc[fm][fn] = __builtin_amdgcn_mfma_f32_16x16x32_bf16(afr[fm], bfr[fn], acc[fm][fn], 0, 0, 0);
  }

  float sc[4], sh[4];
#pragma unroll
  for (int fn = 0; fn < 4; ++fn) {
    int co = wn * 64 + fn * 16 + (l & 15);
    float s = pg[co] / sqrtf(1.f + 1e-5f);
    sc[fn] = s;
    sh[fn] = pb[co] * s + pbe[co];
  }

  __syncthreads();
#pragma unroll
  for (int fm = 0; fm < 4; ++fm)
#pragma unroll
    for (int fn = 0; fn < 4; ++fn) {
      int co = wn * 64 + fn * 16 + (l & 15);
#pragma unroll
      for (int q = 0; q < 4; ++q) {
        int m = wm * 64 + fm * 16 + (l >> 4) * 4 + q;
        float y = fmaxf(acc[fm][fn][q] * sc[fn] + sh[fn], 0.f);
        *(u16*)(lds + m * 256 + ((co * 2) ^ ((m & 15) << 4))) = f2bf(y);
      }
    }
  __syncthreads();
#pragma unroll
  for (int p = 0; p < 8; ++p) {
    int e = p * 256 + t;
    int m = e >> 4;
    int hw = m0 + m;
    if (hw < HW) {
      uint4 v = *(const uint4*)(lds + m * 256 + (((e & 15) * 16) ^ ((m & 15) << 4)));
      *(uint4*)(h1t + ((size_t)n * HW + hw) * CH + (e & 15) * 8) = v;
    }
  }
}

// ---------------------------------------------------------------------------
// dht v4 (gather, deep pipeline): block = (n, a), 1024 thr = 16 waves.
// Lane = channel-pair. Per owned bin: 16 list entries loaded, 16 img gathers
// in flight, 4 independent accumulator pairs (breaks fadd chain). Tails 8/4/1.
// ---------------------------------------------------------------------------
__global__ void __launch_bounds__(1024)
k_dht(const u16* __restrict__ h1t, const u16* __restrict__ list,
      const int* __restrict__ coff, u16* __restrict__ dht) {
  __shared__ int soff[NR + 1];
  int id = blockIdx.x;
  int x  = id & 7;
  int l  = id >> 3;
  int n  = (x << 1) | (l >= 100 ? 1 : 0);
  int a  = (l >= 100) ? l - 100 : l;
  int t  = threadIdx.x;
  int c  = t & 63;
  int w  = t >> 6;

  if (t <= NR) soff[t] = coff[a * (NR + 1) + t];
  __syncthreads();

  const char* imgb = (const char*)h1t + (size_t)n * HW * 256 + c * 4;
  const u16* lst = list + (size_t)a * HW;
  unsigned int* out32 = (unsigned int*)(dht + ((size_t)(n * NA + a) * NR) * CH) + c;

  for (int r = 0; r < NR; ++r) {
    int o0 = soff[r], o1 = soff[r + 1];
    int owner = (o0 + ((o1 - o0) >> 1)) * 16 / HW;
    owner = owner > 15 ? 15 : owner;
    if (owner != w) continue;

    float ax0 = 0.f, ax1 = 0.f, ax2 = 0.f, ax3 = 0.f;
    float ay0 = 0.f, ay1 = 0.f, ay2 = 0.f, ay3 = 0.f;
    int k = o0;

    for (; k + 16 <= o1; k += 16) {
      unsigned int p[16], v[16];
#pragma unroll
      for (int j = 0; j < 16; ++j) p[j] = lst[k + j];
#pragma unroll
      for (int j = 0; j < 16; ++j)
        v[j] = *(const unsigned int*)(imgb + ((size_t)p[j] << 8));
#pragma unroll
      for (int j = 0; j < 16; ++j) {
        float lo = __uint_as_float(v[j] << 16);
        float hi = __uint_as_float(v[j] & 0xffff0000u);
        if ((j & 3) == 0) { ax0 += lo; ay0 += hi; }
        else if ((j & 3) == 1) { ax1 += lo; ay1 += hi; }
        else if ((j & 3) == 2) { ax2 += lo; ay2 += hi; }
        else { ax3 += lo; ay3 += hi; }
      }
    }
    if (k + 8 <= o1) {
      unsigned int p[8], v[8];
#pragma unroll
      for (int j = 0; j < 8; ++j) p[j] = lst[k + j];
#pragma unroll
      for (int j = 0; j < 8; ++j)
        v[j] = *(const unsigned int*)(imgb + ((size_t)p[j] << 8));
#pragma unroll
      for (int j = 0; j < 8; ++j) {
        float lo = __uint_as_float(v[j] << 16);
        float hi = __uint_as_float(v[j] & 0xffff0000u);
        if ((j & 3) == 0) { ax0 += lo; ay0 += hi; }
        else if ((j & 3) == 1) { ax1 += lo; ay1 += hi; }
        else if ((j & 3) == 2) { ax2 += lo; ay2 += hi; }
        else { ax3 += lo; ay3 += hi; }
      }
      k += 8;
    }
    if (k + 4 <= o1) {
      unsigned int p[4], v[4];
#pragma unroll
      for (int j = 0; j < 4; ++j) p[j] = lst[k + j];
#pragma unroll
      for (int j = 0; j < 4; ++j)
        v[j] = *(const unsigned int*)(imgb + ((size_t)p[j] << 8));
      ax0 += __uint_as_float(v[0] << 16); ay0 += __uint_as_float(v[0] & 0xffff0000u);
      ax1 += __uint_as_float(v[1] << 16); ay1 += __uint_as_float(v[1] & 0xffff0000u);
      ax2 += __uint_as_float(v[2] << 16); ay2 += __uint_as_float(v[2] & 0xffff0000u);
      ax3 += __uint_as_float(v[3] << 16); ay3 += __uint_as_float(v[3] & 0xffff0000u);
      k += 4;
    }
    for (; k < o1; ++k) {
      unsigned int v = *(const unsigned int*)(imgb + ((size_t)lst[k] << 8));
      ax0 += __uint_as_float(v << 16);
      ay0 += __uint_as_float(v & 0xffff0000u);
    }

    float ax = (ax0 + ax1) + (ax2 + ax3);
    float ay = (ay0 + ay1) + (ay2 + ay3);
    unsigned int pk = (unsigned int)f2bf(ax) | ((unsigned int)f2bf(ay) << 16);
    out32[(size_t)r << 6] = pk;
  }
}

// ---------------------------------------------------------------------------
// conv3x3 (MFMA implicit GEMM) — unchanged
// ---------------------------------------------------------------------------
template <int OUT_MODE>
__global__ void __launch_bounds__(256)
k_conv3x3(const u16* __restrict__ X, const u16* __restrict__ wbf,
          const float* __restrict__ pb, const float* __restrict__ pg,
          const float* __restrict__ pbe, void* __restrict__ out) {
  __shared__ uint4 lds4[2880];
  char* lds = (char*)lds4;
  int n    = blockIdx.y;
  int tile = blockIdx.x;
  int ta = tile / 13, tr = tile - ta * 13;
  int a0 = ta * 16, r0 = tr * 8;
  int t  = threadIdx.x;
  int l  = t & 63, w = t >> 6, wm = w >> 1, wn = w & 1;

  {
    int sr16 = t >> 4;
    int cb   = (t & 15) * 16;
#pragma unroll
    for (int p = 0; p < 12; ++p) {
      int s = p * 16 + sr16;
      if (s < 180) {
        int sa = a0 - 1 + s / 10;
        int sr = r0 - 1 + s % 10;
        uint4 v = make_uint4(0, 0, 0, 0);
        if (sa >= 0 && sa < NA && sr >= 0 && sr < NR)
          v = *(const uint4*)(X + ((size_t)(n * NA + sa) * NR + sr) * CH + (t & 15) * 8);
        *(uint4*)(lds + s * 256 + (cb ^ ((s & 15) << 4))) = v;
      }
    }
  }
  __syncthreads();

  int sbase[4];
#pragma unroll
  for (int fm = 0; fm < 4; ++fm) {
    int m = wm * 64 + fm * 16 + (l & 15);
    sbase[fm] = ((m >> 3) + 1) * 10 + (m & 7) + 1;
  }
  int kseg = (l >> 4) * 16;

  f32x4 acc[4][4];
  f32x4 zf = {0.f, 0.f, 0.f, 0.f};
#pragma unroll
  for (int i = 0; i < 4; ++i)
#pragma unroll
    for (int j = 0; j < 4; ++j) acc[i][j] = zf;

  for (int tap = 0; tap < 9; ++tap) {
    int soff = (tap / 3 - 1) * 10 + (tap % 3 - 1);
#pragma unroll
    for (int kc = 0; kc < 4; ++kc) {
      short8 afr[4], bfr[4];
#pragma unroll
      for (int fm = 0; fm < 4; ++fm) {
        int s = sbase[fm] + soff;
        afr[fm] = *(const short8*)(lds + s * 256 + ((kc * 64 + kseg) ^ ((s & 15) << 4)));
      }
#pragma unroll
      for (int fn = 0; fn < 4; ++fn)
        bfr[fn] = *(const short8*)(wbf + (((size_t)(tap * 4 + kc) * 8 + wn * 4 + fn) * 64 + l) * 8);
#pragma unroll
      for (int fm = 0; fm < 4; ++fm)
#pragma unroll
        for (int fn = 0; fn < 4; ++fn)
          acc[fm][fn] = __builtin_amdgcn_mfma_f32_16x16x32_bf16(afr[fm], bfr[fn], acc[fm][fn], 0, 0, 0);
    }
  }

  float sc[4], sh[4];
#pragma unroll
  for (int fn = 0; fn < 4; ++fn) {
    int co = wn * 64 + fn * 16 + (l & 15);
    float s = pg[co] / sqrtf(1.f + 1e-5f);
    sc[fn] = s;
    sh[fn] = pb[co] * s + pbe[co];
  }

  if (OUT_MODE == 0) {
    __syncthreads();
#pragma unroll
    for (int fm = 0; fm < 4; ++fm)
#pragma unroll
      for (int fn = 0; fn < 4; ++fn) {
        int co = wn * 64 + fn * 16 + (l & 15);
#pragma unroll
        for (int q = 0; q < 4; ++q) {
          int m = wm * 64 + fm * 16 + (l >> 4) * 4 + q;
          float y = fmaxf(acc[fm][fn][q] * sc[fn] + sh[fn], 0.f);
          *(u16*)(lds + m * 256 + ((co * 2) ^ ((m & 15) << 4))) = f2bf(y);
        }
      }
    __syncthreads();
    u16* o = (u16*)out;
#pragma unroll
    for (int p = 0; p < 8; ++p) {
      int e = p * 256 + t;
      int m = e >> 4;
      int a = a0 + (m >> 3), r = r0 + (m & 7);
      if (a < NA && r < NR) {
        uint4 v = *(const uint4*)(lds + m * 256 + (((e & 15) * 16) ^ ((m & 15) << 4)));
        *(uint4*)(o + ((size_t)(n * NA + a) * NR + r) * CH + (e & 15) * 8) = v;
      }
    }
  } else {
    float* o = (float*)out;
#pragma unroll
    for (int fm = 0; fm < 4; ++fm) {
      int mb = wm * 64 + fm * 16 + (l >> 4) * 4;
      int a  = a0 + (mb >> 3), rr = r0 + (mb & 7);
      if (a < NA && rr < NR) {
#pragma unroll
        for (int fn = 0; fn < 4; ++fn) {
          int co = wn * 64 + fn * 16 + (l & 15);
          float4 v;
          v.x = fmaxf(acc[fm][fn][0] * sc[fn] + sh[fn], 0.f);
          v.y = fmaxf(acc[fm][fn][1] * sc[fn] + sh[fn], 0.f);
          v.z = fmaxf(acc[fm][fn][2] * sc[fn] + sh[fn], 0.f);
          v.w = fmaxf(acc[fm][fn][3] * sc[fn] + sh[fn], 0.f);
          *(float4*)(o + ((size_t)n * CH + co) * HW + a * NR + rr) = v;
        }
      }
    }
  }
}

// ---------------------------------------------------------------------------
extern "C" void kernel_launch(void* const* d_in, const int* in_sizes, int n_in,
                              void* d_out, int out_size, void* d_ws, size_t ws_size,
                              hipStream_t stream) {
  if (n_in < 13) return;
  const float* x   = (const float*)d_in[0];
  const float* w1  = (const float*)d_in[1];
  const float* b1  = (const float*)d_in[2];
  const float* g1  = (const float*)d_in[3];
  const float* be1 = (const float*)d_in[4];
  const float* w2  = (const float*)d_in[5];
  const float* b2  = (const float*)d_in[6];
  const float* g2  = (const float*)d_in[7];
  const float* be2 = (const float*)d_in[8];
  const float* w3  = (const float*)d_in[9];
  const float* b3  = (const float*)d_in[10];
  const float* g3  = (const float*)d_in[11];
  const float* be3 = (const float*)d_in[12];

  // workspace layout (256B-aligned)
  const size_t o_list = 0;                    // u16[100][10000]      = 2,000,000
  const size_t o_coff = 2000128;              // int[100][101]        =    40,400
  const size_t o_wbf1 = 2040576;              // u16[32768]           =    65,536
  const size_t o_wbf2 = o_wbf1 + 65536;       // u16[147456]          =   294,912
  const size_t o_wbf3 = o_wbf2 + 294912;      // u16[147456]          =   294,912
  const size_t o_dht  = o_wbf3 + 294912;      // 40,960,000 (xt overlays dht+c2: 81,920,000)
  const size_t o_c2   = o_dht + 40960000;     // 40,960,000
  const size_t need   = o_dht + 81920000;     // ~84.6 MB
  if (ws_size < need) return;

  char*  ws   = (char*)d_ws;
  u16*   list = (u16*)(ws + o_list);
  int*   coff = (int*)(ws + o_coff);
  u16*   wbf1 = (u16*)(ws + o_wbf1);
  u16*   wbf2 = (u16*)(ws + o_wbf2);
  u16*   wbf3 = (u16*)(ws + o_wbf3);
  u16*   xt   = (u16*)(ws + o_dht);   // dead after k_conv1
  u16*   dht  = (u16*)(ws + o_dht);   // written by k_dht after xt is dead
  u16*   c2   = (u16*)(ws + o_c2);
  u16*   h1t  = (u16*)d_out;          // bf16 scratch inside f32 out (dead before conv3)

  k_prep<<<dim3(576), dim3(256), 0, stream>>>(w1, w2, w3, wbf1, wbf2, wbf3);
  k_csr<<<dim3(100), dim3(256), 0, stream>>>(list, coff);
  k_xt<<<dim3(157, 4, 16), dim3(256), 0, stream>>>(x, xt);
  k_conv1<<<dim3(79, 16), dim3(256), 0, stream>>>(xt, wbf1, b1, g1, be1, h1t);
  k_dht<<<dim3(1600), dim3(1024), 0, stream>>>(h1t, list, coff, dht);
  k_conv3x3<0><<<dim3(91, 16), dim3(256), 0, stream>>>(dht, wbf2, b2, g2, be2, (void*)c2);
  k_conv3x3<1><<<dim3(91, 16), dim3(256), 0, stream>>>(c2, wbf3, b3, g3, be3, d_out);
}